// Round 7
// baseline (171.497 us; speedup 1.0000x reference)
//
#include <hip/hip_runtime.h>

#define BSZ   32
#define SEQ   64
#define HID   256
#define G4    1024
#define NSTEP 64
#define QB    16     // blocks per batch
#define JB    16     // hidden units per block

typedef unsigned long long u64;
typedef unsigned int       u32;

__device__ __forceinline__ float sigmoidf_(float v) { return 1.f / (1.f + __expf(-v)); }

// ---------------------------------------------------------------------------
// Single fused kernel. grid = 512 = 32 b x 16 q, decoded b = idx&31, q = idx>>5
// => XCD = idx%8 = b%8: all 16 siblings of a batch share one XCD's L2.
// LDS ~76KB => 2 blocks/CU co-resident: one block's publish->poll RT hides
// under the co-resident block's MAC (the R6 bottleneck was this latency
// sitting serially on a 1-block/CU critical path).
//
// Block (b,q) owns hidden j in [q*16, q*16+16) => 64 W columns in LDS,
// layout arena[k*64 + g*16 + j] (= global layout slice, straight f4 staging).
//
// Step map: cq = tid&15 (col-quad: g = cq>>2, j = (cq&3)*4..+3),
//           kq = tid>>4 (k-slice of 16).
// All W reads: 16-lane phase = 16 consecutive f4 = 256B => 2-way banks (free).
// h reads: 16-lane same-address broadcast (free).
// h staging is 16-group-local (reader kq reads words staged by tids
// kq*16..+15 = itself and wave-mates; divergent poll exits only when the
// whole wave's words arrived) => no post-stage barrier. One barrier/step.
// Reduce: wave 0, lane=col (64 cols), fan-in 16 + bias/Gc in register;
// 3x shfl_xor(16/32/48) gate-gather; lanes 0..15 pointwise + tagged publish.
// Sync: tagged 8B words {f32 hi | tag lo}, relaxed agent-scope atomics,
// parity double-buffer for tht & gred. 0xAA ws-poison never matches tags.
// ---------------------------------------------------------------------------
__global__ __launch_bounds__(256, 2) void k_fused(
    const float* __restrict__ x, const float* __restrict__ Wa,
    const float* __restrict__ Wi, const float* __restrict__ Wh,
    const float* __restrict__ bias, const float* __restrict__ Wf,
    const float* __restrict__ bf,
    u64* __restrict__ tht, u64* __restrict__ ctxT, float* __restrict__ out)
{
  const int b    = blockIdx.x & 31;   // siblings of a batch share an XCD
  const int q    = blockIdx.x >> 5;   // 0..15
  const int tid  = threadIdx.x;
  const int lane = tid & 63;
  const int wv   = tid >> 6;
  const int cq   = tid & 15;          // col-quad (cols cq*4..+3 of [g*16+j])
  const int kq   = tid >> 4;          // k-slice (16 k each)

  // arena (floats): phase B/C: W[256][64] @0 (16384); hs @16384; cs @16640;
  //                 gred @16896 (2*16*64) -> 18944 total (75.8KB)
  //                 phase A : xs[64][68] @0; was[64][16] @4352; Ls[64][20] @5376
  __shared__ __align__(16) float arena[18944];
  __shared__ float red[4];
  float* xs   = arena;            // [64][68]
  float* was  = arena + 4352;     // [64][16]
  float* Ls   = arena + 5376;     // [64][20]
  float* hs   = arena + 16384;    // [256]
  float* cs   = arena + 16640;    // [256]
  float* gred = arena + 16896;    // [2][16][64]

  const float* xb = x + (size_t)b * SEQ * HID;

  // =================== phase A: context slice (k-chunked) ===================
  float l0 = 0.f, l1 = 0.f, l2 = 0.f, l3 = 0.f;
  const int ts = tid >> 2, tc = tid & 3;
  for (int kt = 0; kt < 4; ++kt) {
    __syncthreads();                          // protect previous chunk reads
#pragma unroll
    for (int i = 0; i < 4; ++i) {             // stage xs[64][64] chunk
      const int f = i * 256 + tid;
      const int s = f >> 4, kc = (f & 15) * 4;
      *(float4*)&xs[s * 68 + kc] = *(const float4*)(xb + s * HID + kt * 64 + kc);
    }
    {                                         // stage Wa chunk [64][16]
      const int k = tid >> 2, jw = tid & 3;
      *(float4*)&was[k * 16 + jw * 4] =
          *(const float4*)(Wa + (size_t)(kt * 64 + k) * HID + q * JB + jw * 4);
    }
    __syncthreads();
#pragma unroll
    for (int k4 = 0; k4 < 16; ++k4) {         // logits partial
      const float4 xv = *(const float4*)&xs[ts * 68 + k4 * 4];
#pragma unroll
      for (int e = 0; e < 4; ++e) {
        const float xe = (e == 0) ? xv.x : (e == 1) ? xv.y : (e == 2) ? xv.z : xv.w;
        const float4 w4 = *(const float4*)&was[(k4 * 4 + e) * 16 + tc * 4];
        l0 += xe * w4.x; l1 += xe * w4.y; l2 += xe * w4.z; l3 += xe * w4.w;
      }
    }
  }
  {
    float* lr = &Ls[ts * 20 + tc * 4];
    lr[0] = l0; lr[1] = l1; lr[2] = l2; lr[3] = l3;
  }
  __syncthreads();

  {  // softmax over s (shift-invariance: ht/ct/ba cancel) + ctx publish
    const int jx = tid >> 4, sp = tid & 15;   // 16 j x 16 sp (4 s each)
    float lg[4];
#pragma unroll
    for (int e = 0; e < 4; ++e) lg[e] = Ls[(sp * 4 + e) * 20 + jx];
    float m = fmaxf(fmaxf(lg[0], lg[1]), fmaxf(lg[2], lg[3]));
    m = fmaxf(m, __shfl_xor(m, 1));
    m = fmaxf(m, __shfl_xor(m, 2));
    m = fmaxf(m, __shfl_xor(m, 4));
    m = fmaxf(m, __shfl_xor(m, 8));
    float ex[4], sm = 0.f;
#pragma unroll
    for (int e = 0; e < 4; ++e) { ex[e] = __expf(lg[e] - m); sm += ex[e]; }
    sm += __shfl_xor(sm, 1);
    sm += __shfl_xor(sm, 2);
    sm += __shfl_xor(sm, 4);
    sm += __shfl_xor(sm, 8);
    const float inv = 1.f / sm;
    const int gj = q * JB + jx;
    float cx = 0.f;
#pragma unroll
    for (int e = 0; e < 4; ++e) cx += ex[e] * xb[(sp * 4 + e) * HID + gj];
    cx *= inv;
    cx += __shfl_xor(cx, 1);
    cx += __shfl_xor(cx, 2);
    cx += __shfl_xor(cx, 4);
    cx += __shfl_xor(cx, 8);
    if (sp == 0)
      __hip_atomic_store(ctxT + b * HID + gj,
                         (((u64)__float_as_uint(cx)) << 32) | 1ull,
                         __ATOMIC_RELAXED, __HIP_MEMORY_SCOPE_AGENT);
  }
  __syncthreads();   // all xs/was/Ls reads done -> arena reusable

  // 16-k-slice MAC vs LDS W tile — all ds_read_b128, conflict-free.
  // ACC.e = gate g, hidden j=(cq&3)*4+e partial over k = kq*16..+15.
#define MAC16(HSRC, ACC)                                                     \
  _Pragma("unroll")                                                          \
  for (int k4 = 0; k4 < 4; ++k4) {                                           \
    const float4 h4 = *(const float4*)&(HSRC)[kq * 16 + k4 * 4];             \
    const float* wp = &arena[(kq * 16 + k4 * 4) * 64 + cq * 4];              \
    const float4 w0 = *(const float4*)&wp[0];                                \
    const float4 w1 = *(const float4*)&wp[64];                               \
    const float4 w2 = *(const float4*)&wp[128];                              \
    const float4 w3 = *(const float4*)&wp[192];                              \
    ACC.x += h4.x * w0.x + h4.y * w1.x + h4.z * w2.x + h4.w * w3.x;          \
    ACC.y += h4.x * w0.y + h4.y * w1.y + h4.z * w2.y + h4.w * w3.y;          \
    ACC.z += h4.x * w0.z + h4.y * w1.z + h4.z * w2.z + h4.w * w3.z;          \
    ACC.w += h4.x * w0.w + h4.y * w1.w + h4.z * w2.w + h4.w * w3.w;          \
  }

  // =================== phase B: Wi tile, ctx poll, Gc ===================
#pragma unroll
  for (int i = 0; i < 16; ++i) {              // stage Wi slice [k][64]
    const int f = i * 256 + tid;
    const int k = f >> 4, c4 = f & 15, gg = c4 >> 2, jw = c4 & 3;
    *(float4*)&arena[f * 4] =
        *(const float4*)(Wi + (size_t)k * G4 + gg * HID + q * JB + jw * 4);
  }
  {  // poll full ctx (tag=1) -> cs
    const u64* pp = ctxT + b * HID + tid;
    u64 pk;
    do {
      pk = __hip_atomic_load(pp, __ATOMIC_RELAXED, __HIP_MEMORY_SCOPE_AGENT);
    } while ((u32)pk != 1u);
    cs[tid] = __uint_as_float((u32)(pk >> 32));
  }
  __syncthreads();

  float4 ac = {0.f, 0.f, 0.f, 0.f};
  MAC16(cs, ac);
  *(float4*)&gred[kq * 64 + cq * 4] = ac;     // parity 0
  __syncthreads();

  float gc = 0.f, cst = 0.f;                  // per-col Gc(+bias), c state
  if (wv == 0) {                              // reducer wave: col = lane
#pragma unroll
    for (int k2 = 0; k2 < 16; ++k2) gc += gred[k2 * 64 + lane];
    gc += bias[(lane >> 4) * HID + q * JB + (lane & 15)];
    // step 0 (h=0): gates = Gc; publish tag 1 (overlaps Wh staging below)
    const float gx2 = __shfl_xor(gc, 32), ox = __shfl_xor(gc, 48);
    if (lane < 16) {
      const float ig = sigmoidf_(gc);
      const float g2 = tanhf(gx2), og = sigmoidf_(ox);
      cst = ig * g2;
      const float hv = og * tanhf(cst);
      __hip_atomic_store(tht + (size_t)BSZ * HID + (size_t)b * HID + q * JB + lane,
                         (((u64)__float_as_uint(hv)) << 32) | 1ull,
                         __ATOMIC_RELAXED, __HIP_MEMORY_SCOPE_AGENT);
    }
  }
#pragma unroll
  for (int i = 0; i < 16; ++i) {              // stage Wh (overwrites Wi tile)
    const int f = i * 256 + tid;
    const int k = f >> 4, c4 = f & 15, gg = c4 >> 2, jw = c4 & 3;
    *(float4*)&arena[f * 4] =
        *(const float4*)(Wh + (size_t)k * G4 + gg * HID + q * JB + jw * 4);
  }
  __syncthreads();

  // =================== phase C: recurrent steps 1..63 ===================
  for (int t = 1; t < NSTEP; ++t) {
    const int rb = t & 1;
    {
      const u64* pp = tht + (size_t)rb * BSZ * HID + (size_t)b * HID + tid;
      u64 pk;
      do {
        pk = __hip_atomic_load(pp, __ATOMIC_RELAXED, __HIP_MEMORY_SCOPE_AGENT);
      } while ((u32)pk != (u32)t);
      hs[tid] = __uint_as_float((u32)(pk >> 32));
    }
    // hs RAW is 16-group-local (reader kq reads words staged by tids
    // kq*16..+15 of its own wave; wave exits poll only when all lanes have
    // their word; same-wave LDS ops are program-ordered).
    float4 a2 = {0.f, 0.f, 0.f, 0.f};
    MAC16(hs, a2);
    *(float4*)&gred[rb * 1024 + kq * 64 + cq * 4] = a2;
    __syncthreads();

    if (wv == 0) {   // reducer: col = lane; 16 partials + Gc
      float s_ = gc;
#pragma unroll
      for (int k2 = 0; k2 < 16; ++k2) s_ += gred[rb * 1024 + k2 * 64 + lane];
      const float fx  = __shfl_xor(s_, 16);
      const float gx2 = __shfl_xor(s_, 32);
      const float ox  = __shfl_xor(s_, 48);
      if (lane < 16) {   // own=i, ^16=f, ^32=g, ^48=o for hidden j=lane
        const float ig = sigmoidf_(s_), fg = sigmoidf_(fx);
        const float g2 = tanhf(gx2),    og = sigmoidf_(ox);
        cst = fg * cst + ig * g2;
        const float hv = og * tanhf(cst);
        __hip_atomic_store(tht + (size_t)((t + 1) & 1) * BSZ * HID
                               + (size_t)b * HID + q * JB + lane,
                           (((u64)__float_as_uint(hv)) << 32) | (u64)(u32)(t + 1),
                           __ATOMIC_RELAXED, __HIP_MEMORY_SCOPE_AGENT);
      }
    }
    // gred parity WAR-free: iter-t reduce reads gred[t&1] after barrier(t);
    // the next write to gred[t&1] (iter t+2) follows barrier(t+1), which
    // follows the reducer's iter-t reads. One barrier per step.
  }

  // =================== epilogue: out[b] = ht @ Wf + bf ===================
  if (q == 0) {
    const u64* pp = tht + /*parity 0*/ (size_t)b * HID + tid;
    u64 pk;
    do {
      pk = __hip_atomic_load(pp, __ATOMIC_RELAXED, __HIP_MEMORY_SCOPE_AGENT);
    } while ((u32)pk != (u32)NSTEP);
    const float hv = __uint_as_float((u32)(pk >> 32));
    float prod = hv * Wf[tid];
#pragma unroll
    for (int mk = 1; mk < 64; mk <<= 1) prod += __shfl_xor(prod, mk);
    if (lane == 0) red[wv] = prod;
    __syncthreads();
    if (tid == 0) out[b] = red[0] + red[1] + red[2] + red[3] + bf[0];
  }
#undef MAC16
}

// ---------------------------------------------------------------------------
extern "C" void kernel_launch(void* const* d_in, const int* in_sizes, int n_in,
                              void* d_out, int out_size, void* d_ws, size_t ws_size,
                              hipStream_t stream)
{
  const float* x  = (const float*)d_in[0];
  const float* Wa = (const float*)d_in[1];
  // d_in[2] = ba: unused — constant along softmax axis, cancels exactly
  const float* Wi = (const float*)d_in[3];
  const float* Wh = (const float*)d_in[4];
  const float* bi = (const float*)d_in[5];
  const float* Wf = (const float*)d_in[6];
  const float* bf = (const float*)d_in[7];
  float* out = (float*)d_out;

  // ws: [0,128KB) tagged ht (2 parity bufs); [128KB,192KB) tagged ctx
  u64* tht  = (u64*)d_ws;
  u64* ctxT = (u64*)((char*)d_ws + 2 * BSZ * HID * sizeof(u64));

  hipLaunchKernelGGL(k_fused, dim3(BSZ * QB), dim3(256), 0, stream,
                     x, Wa, Wi, Wh, bi, Wf, bf, tht, ctxT, out);
}